// Round 9
// baseline (110.638 us; speedup 1.0000x reference)
//
#include <hip/hip_runtime.h>
#include <math.h>

#define N_ROWS 4096
#define DIM 256
constexpr float INV_T = 10.0f;

#define NT 32                   // 4096 / 128 tiles per view side
#define NTILES 528              // NT*(NT+1)/2 upper-triangular tiles
#define BM 128
#define PSTRIDE 512             // [2x128 row partials (per wx) | 2x128 col partials (per wy)]

typedef __attribute__((ext_vector_type(8))) short short8;   // bf16x8 MFMA operand
typedef __attribute__((ext_vector_type(4))) float floatx4;  // fp32x4 accumulator

__device__ __forceinline__ unsigned short f2bf(float f) {
    unsigned int u = __float_as_uint(f);
    return (unsigned short)((u + 0x7FFFu + ((u >> 16) & 1u)) >> 16);  // RNE
}

// Kernel 1: one wave per row. L2-normalized bf16 rows of z_j -> R0, z_i -> R1,
// pos[r] = dot(zi_n, zj_n)*10. Thread (0,0) zeroes the scalar output.
__global__ __launch_bounds__(256) void normalize_kernel(
    const float* __restrict__ z_i, const float* __restrict__ z_j,
    unsigned short* __restrict__ R0, unsigned short* __restrict__ R1,
    float* __restrict__ pos, float* __restrict__ out)
{
    if (blockIdx.x == 0 && threadIdx.x == 0) out[0] = 0.0f;

    int wave = threadIdx.x >> 6;
    int lane = threadIdx.x & 63;
    int row = blockIdx.x * 4 + wave;

    float4 a = ((const float4*)(z_i + (size_t)row * DIM))[lane];
    float4 b = ((const float4*)(z_j + (size_t)row * DIM))[lane];

    float ssa = a.x*a.x + a.y*a.y + a.z*a.z + a.w*a.w;
    float ssb = b.x*b.x + b.y*b.y + b.z*b.z + b.w*b.w;
    float dab = a.x*b.x + a.y*b.y + a.z*b.z + a.w*b.w;
    #pragma unroll
    for (int off = 1; off < 64; off <<= 1) {
        ssa += __shfl_xor(ssa, off);
        ssb += __shfl_xor(ssb, off);
        dab += __shfl_xor(dab, off);
    }
    float ra = rsqrtf(ssa);
    float rb = rsqrtf(ssb);

    ushort4 ua, ub;
    ua.x = f2bf(a.x * ra); ua.y = f2bf(a.y * ra); ua.z = f2bf(a.z * ra); ua.w = f2bf(a.w * ra);
    ub.x = f2bf(b.x * rb); ub.y = f2bf(b.y * rb); ub.z = f2bf(b.z * rb); ub.w = f2bf(b.w * rb);
    ((ushort4*)(R1 + (size_t)row * DIM))[lane] = ua;   // zi_norm
    ((ushort4*)(R0 + (size_t)row * DIM))[lane] = ub;   // zj_norm

    if (lane == 0) pos[row] = dab * ra * rb * INV_T;
}

// Kernel 2: symmetric fused GEMM, upper-triangular 128x128 tiles (x2 views).
// NO LDS, NO barriers: both operands' MFMA fragments are contiguous 16B
// K-chunks of row-major R (B^T-form GEMM), loaded directly with
// global_load_dwordx4 from the L2-resident 4MB input. Wave-pair A/B sharing
// is served by L1/L2. Hand-pipelined K-loop (cur/next fragment buffers) so
// the compiler can't hoist all 64 loads into a register spill.
// Epilogue: exp(10*S), diagonal excluded; ROW partials per (tile,wx-wave),
// COL partials per (tile,wy-wave), plain coalesced stores, unique slot per
// wave. No atomics, no completion counter, no fence.
__global__ __launch_bounds__(256) void gemm_sym(
    const unsigned short* __restrict__ R0,
    const unsigned short* __restrict__ R1,
    float* __restrict__ part)             // [2][NTILES][PSTRIDE]
{
    int view = blockIdx.y;
    const unsigned short* R = view ? R1 : R0;
    float* P = part + (size_t)(view * NTILES + blockIdx.x) * PSTRIDE;

    // triangular decode: blockIdx.x -> (by, bx), bx >= by
    int t = blockIdx.x;
    int by = 0;
    while (t >= NT - by) { t -= NT - by; ++by; }
    int bx = by + t;
    int rT = by * BM, cT = bx * BM;

    int tid = threadIdx.x;
    int lane = tid & 63;
    int wave = tid >> 6;
    int wy = wave >> 1, wx = wave & 1;
    int m = lane & 15, q = lane >> 4;

    // Fragment bases: A row (rT+wy*64+t*16+m), B row (cT+wx*64+t*16+m),
    // K-chunk q*8 + kk*32. All 16B-aligned contiguous loads.
    const unsigned short* Abase = R + (size_t)(rT + wy * 64 + m) * DIM + q * 8;
    const unsigned short* Bbase = R + (size_t)(cT + wx * 64 + m) * DIM + q * 8;

    floatx4 acc[4][4] = {};
    short8 fa[2][4], fb[2][4];

    #pragma unroll
    for (int tt = 0; tt < 4; ++tt) {
        fa[0][tt] = *(const short8*)(Abase + (size_t)tt * 16 * DIM);
        fb[0][tt] = *(const short8*)(Bbase + (size_t)tt * 16 * DIM);
    }

    #pragma unroll
    for (int kk = 0; kk < 8; ++kk) {
        int cur = kk & 1, nxt = cur ^ 1;
        if (kk < 7) {
            int ko = (kk + 1) * 32;
            #pragma unroll
            for (int tt = 0; tt < 4; ++tt) {
                fa[nxt][tt] = *(const short8*)(Abase + (size_t)tt * 16 * DIM + ko);
                fb[nxt][tt] = *(const short8*)(Bbase + (size_t)tt * 16 * DIM + ko);
            }
        }
        #pragma unroll
        for (int i = 0; i < 4; ++i)
            #pragma unroll
            for (int j = 0; j < 4; ++j)
                acc[i][j] = __builtin_amdgcn_mfma_f32_16x16x32_bf16(fa[cur][i], fb[cur][j], acc[i][j], 0, 0, 0);
    }

    // Epilogue. C/D layout: col = m, row = q*4 + r (m89/m91).
    float rs[4][4] = {};
    float cs[4] = {0.f, 0.f, 0.f, 0.f};
    #pragma unroll
    for (int i = 0; i < 4; ++i) {
        #pragma unroll
        for (int j = 0; j < 4; ++j) {
            int gcol = cT + wx * 64 + j * 16 + m;
            #pragma unroll
            for (int r = 0; r < 4; ++r) {
                int grow = rT + wy * 64 + i * 16 + q * 4 + r;
                float e = (grow == gcol) ? 0.0f : __expf(acc[i][j][r] * INV_T);
                rs[i][r] += e;
                cs[j] += e;
            }
        }
    }
    // Row partials: reduce over the 16 column-lanes (m); per-(wx,wy) slot.
    #pragma unroll
    for (int off = 1; off < 16; off <<= 1)
        #pragma unroll
        for (int i = 0; i < 4; ++i)
            #pragma unroll
            for (int r = 0; r < 4; ++r)
                rs[i][r] += __shfl_xor(rs[i][r], off);
    if (m == 0) {
        #pragma unroll
        for (int i = 0; i < 4; ++i) {
            float4 v = make_float4(rs[i][0], rs[i][1], rs[i][2], rs[i][3]);
            *(float4*)&P[wx * 128 + wy * 64 + i * 16 + q * 4] = v;
        }
    }
    // Col partials: reduce over the 4 row-quads (q); per-(wy,wx) slot.
    // Diagonal tiles store 0 (their block is fully covered by the row sums).
    #pragma unroll
    for (int off = 16; off < 64; off <<= 1)
        #pragma unroll
        for (int j = 0; j < 4; ++j)
            cs[j] += __shfl_xor(cs[j], off);
    if (q == 0) {
        #pragma unroll
        for (int j = 0; j < 4; ++j)
            P[256 + wy * 128 + wx * 64 + j * 16 + m] = (bx == by) ? 0.0f : cs[j];
    }
}

// Kernel 3: per-row denom gather (L2-resident) + loss reduce.
__global__ __launch_bounds__(256) void finalize_kernel(
    const float* __restrict__ part, const float* __restrict__ pos,
    float* __restrict__ out)
{
    int g = blockIdx.x * 256 + threadIdx.x;      // 0..8191
    int v = g >> 12, r = g & (N_ROWS - 1);
    int b = r >> 7, l = r & 127;
    const float* P = part + (size_t)v * NTILES * PSTRIDE;

    float d = 0.f;
    int t0 = b * NT - (b * (b - 1)) / 2;         // tile (b, b)
    for (int k = 0; k < NT - b; ++k) {           // row parts: tiles (b, bx>=b)
        const float* T = P + (size_t)(t0 + k) * PSTRIDE;
        d += T[l] + T[128 + l];                  // both wx halves
    }
    for (int by = 0; by <= b; ++by) {            // col parts: tiles (by<=b, b)
        int tb = by * NT - (by * (by - 1)) / 2 + (b - by);
        const float* T = P + (size_t)tb * PSTRIDE;
        d += T[256 + l] + T[384 + l];            // both wy halves
    }
    float p = pos[r];
    float s = __logf(d + __expf(p)) - p;
    #pragma unroll
    for (int off = 1; off < 64; off <<= 1) s += __shfl_xor(s, off);
    if ((threadIdx.x & 63) == 0)
        atomicAdd(out, s * (1.0f / (2 * N_ROWS)));
}

extern "C" void kernel_launch(void* const* d_in, const int* in_sizes, int n_in,
                              void* d_out, int out_size, void* d_ws, size_t ws_size,
                              hipStream_t stream) {
    const float* z_i = (const float*)d_in[0];
    const float* z_j = (const float*)d_in[1];
    char* ws = (char*)d_ws;
    unsigned short* R0 = (unsigned short*)ws;                        // 2 MB
    unsigned short* R1 = (unsigned short*)(ws + (2u << 20));         // 2 MB
    float* pos  = (float*)(ws + (4u << 20));                         // 16 KB
    float* part = (float*)(ws + (4u << 20) + (64u << 10));           // 2.1 MB

    normalize_kernel<<<N_ROWS / 4, 256, 0, stream>>>(z_i, z_j, R0, R1, pos,
                                                     (float*)d_out);
    dim3 grid(NTILES, 2);
    gemm_sym<<<grid, 256, 0, stream>>>(R0, R1, part);
    finalize_kernel<<<2 * N_ROWS / 256, 256, 0, stream>>>(part, pos, (float*)d_out);
}

// Round 10
// 98.660 us; speedup vs baseline: 1.1214x; 1.1214x over previous
//
#include <hip/hip_runtime.h>
#include <math.h>

#define N_ROWS 4096
#define DIM 256
constexpr float INV_T = 10.0f;

#define NT 32                   // 4096 / 128 tiles per view side
#define NTILES 528              // NT*(NT+1)/2 upper-triangular tiles
#define BM 128
#define PSTRIDE 512             // [2x128 row partials (per wx) | 2x128 col partials (per wy)]
// Fragment-major layout: element (row,k) of a view lives at
//   F[(row>>4)*4096 + (k>>3)*128 + (row&15)*8 + (k&7)]
// so a wave's MFMA fragment (16 rows x 8 k, lane=(q*16+m)) is a CONTIGUOUS
// 1 KB block: per-lane offset = lane*16 B. 4096 elems per 16-row group.

typedef __attribute__((ext_vector_type(8))) short short8;   // bf16x8 MFMA operand
typedef __attribute__((ext_vector_type(4))) float floatx4;  // fp32x4 accumulator

__device__ __forceinline__ unsigned short f2bf(float f) {
    unsigned int u = __float_as_uint(f);
    return (unsigned short)((u + 0x7FFFu + ((u >> 16) & 1u)) >> 16);  // RNE
}

// Kernel 1: one wave per row. L2-normalize; write bf16 in FRAGMENT-MAJOR
// layout (see above). zj_n -> R0, zi_n -> R1; pos[r] = dot(zi_n,zj_n)*10.
__global__ __launch_bounds__(256) void normalize_kernel(
    const float* __restrict__ z_i, const float* __restrict__ z_j,
    unsigned short* __restrict__ R0, unsigned short* __restrict__ R1,
    float* __restrict__ pos, float* __restrict__ out)
{
    if (blockIdx.x == 0 && threadIdx.x == 0) out[0] = 0.0f;

    int wave = threadIdx.x >> 6;
    int lane = threadIdx.x & 63;
    int row = blockIdx.x * 4 + wave;

    float4 a = ((const float4*)(z_i + (size_t)row * DIM))[lane];   // k = lane*4..+3
    float4 b = ((const float4*)(z_j + (size_t)row * DIM))[lane];

    float ssa = a.x*a.x + a.y*a.y + a.z*a.z + a.w*a.w;
    float ssb = b.x*b.x + b.y*b.y + b.z*b.z + b.w*b.w;
    float dab = a.x*b.x + a.y*b.y + a.z*b.z + a.w*b.w;
    #pragma unroll
    for (int off = 1; off < 64; off <<= 1) {
        ssa += __shfl_xor(ssa, off);
        ssb += __shfl_xor(ssb, off);
        dab += __shfl_xor(dab, off);
    }
    float ra = rsqrtf(ssa);
    float rb = rsqrtf(ssb);

    ushort4 ua, ub;
    ua.x = f2bf(a.x * ra); ua.y = f2bf(a.y * ra); ua.z = f2bf(a.z * ra); ua.w = f2bf(a.w * ra);
    ub.x = f2bf(b.x * rb); ub.y = f2bf(b.y * rb); ub.z = f2bf(b.z * rb); ub.w = f2bf(b.w * rb);

    // k = lane*4 -> chunk c = lane>>1, half h = lane&1
    size_t fo = (size_t)(row >> 4) * 4096 + (lane >> 1) * 128 + (row & 15) * 8 + (lane & 1) * 4;
    *(ushort4*)(R1 + fo) = ua;   // zi_norm
    *(ushort4*)(R0 + fo) = ub;   // zj_norm

    if (lane == 0) pos[row] = dab * ra * rb * INV_T;
}

// Kernel 2: symmetric fused GEMM, upper-triangular 128x128 tiles (x2 views).
// NO LDS, NO barriers: fragment-major R makes every MFMA fragment a single
// contiguous 1 KB coalesced global load (lane offset = lane*16 B), served by
// L1/L2 (4 MB input, L2-resident). Hand-pipelined cur/next fragment regs.
// Epilogue: exp(10*S), diagonal excluded; ROW partials per (tile,wx-wave),
// COL partials per (tile,wy-wave), plain coalesced stores, unique slot per
// wave. No atomics, no completion counter, no fence.
__global__ __launch_bounds__(256) void gemm_sym(
    const unsigned short* __restrict__ R0,
    const unsigned short* __restrict__ R1,
    float* __restrict__ part)             // [2][NTILES][PSTRIDE]
{
    int view = blockIdx.y;
    const unsigned short* R = view ? R1 : R0;
    float* P = part + (size_t)(view * NTILES + blockIdx.x) * PSTRIDE;

    // triangular decode: blockIdx.x -> (by, bx), bx >= by
    int t = blockIdx.x;
    int by = 0;
    while (t >= NT - by) { t -= NT - by; ++by; }
    int bx = by + t;
    int rT = by * BM, cT = bx * BM;

    int tid = threadIdx.x;
    int lane = tid & 63;
    int wave = tid >> 6;
    int wy = wave >> 1, wx = wave & 1;
    int m = lane & 15, q = lane >> 4;

    // Fragment pointers: group g, chunk (kk*4+q), lane offset m*8.
    // af[tt] @ kk = Aptr + tt*4096 + kk*512   (elems; 8192 B / 1024 B steps)
    const unsigned short* Aptr = R + (size_t)((rT >> 4) + wy * 4) * 4096 + q * 128 + m * 8;
    const unsigned short* Bptr = R + (size_t)((cT >> 4) + wx * 4) * 4096 + q * 128 + m * 8;

    floatx4 acc[4][4] = {};
    short8 fa[2][4], fb[2][4];

    #pragma unroll
    for (int tt = 0; tt < 4; ++tt) {
        fa[0][tt] = *(const short8*)(Aptr + tt * 4096);
        fb[0][tt] = *(const short8*)(Bptr + tt * 4096);
    }

    #pragma unroll
    for (int kk = 0; kk < 8; ++kk) {
        int cur = kk & 1, nxt = cur ^ 1;
        if (kk < 7) {
            int ko = (kk + 1) * 512;
            #pragma unroll
            for (int tt = 0; tt < 4; ++tt) {
                fa[nxt][tt] = *(const short8*)(Aptr + tt * 4096 + ko);
                fb[nxt][tt] = *(const short8*)(Bptr + tt * 4096 + ko);
            }
        }
        #pragma unroll
        for (int i = 0; i < 4; ++i)
            #pragma unroll
            for (int j = 0; j < 4; ++j)
                acc[i][j] = __builtin_amdgcn_mfma_f32_16x16x32_bf16(fa[cur][i], fb[cur][j], acc[i][j], 0, 0, 0);
    }

    // Epilogue. C/D layout: col = m, row = q*4 + r (m89/m91).
    float rs[4][4] = {};
    float cs[4] = {0.f, 0.f, 0.f, 0.f};
    #pragma unroll
    for (int i = 0; i < 4; ++i) {
        #pragma unroll
        for (int j = 0; j < 4; ++j) {
            int gcol = cT + wx * 64 + j * 16 + m;
            #pragma unroll
            for (int r = 0; r < 4; ++r) {
                int grow = rT + wy * 64 + i * 16 + q * 4 + r;
                float e = (grow == gcol) ? 0.0f : __expf(acc[i][j][r] * INV_T);
                rs[i][r] += e;
                cs[j] += e;
            }
        }
    }
    // Row partials: reduce over the 16 column-lanes (m); per-(wx,wy) slot.
    #pragma unroll
    for (int off = 1; off < 16; off <<= 1)
        #pragma unroll
        for (int i = 0; i < 4; ++i)
            #pragma unroll
            for (int r = 0; r < 4; ++r)
                rs[i][r] += __shfl_xor(rs[i][r], off);
    if (m == 0) {
        #pragma unroll
        for (int i = 0; i < 4; ++i) {
            float4 v = make_float4(rs[i][0], rs[i][1], rs[i][2], rs[i][3]);
            *(float4*)&P[wx * 128 + wy * 64 + i * 16 + q * 4] = v;
        }
    }
    // Col partials: reduce over the 4 row-quads (q); per-(wy,wx) slot.
    // Diagonal tiles store 0 (their block is fully covered by the row sums).
    #pragma unroll
    for (int off = 16; off < 64; off <<= 1)
        #pragma unroll
        for (int j = 0; j < 4; ++j)
            cs[j] += __shfl_xor(cs[j], off);
    if (q == 0) {
        #pragma unroll
        for (int j = 0; j < 4; ++j)
            P[256 + wy * 128 + wx * 64 + j * 16 + m] = (bx == by) ? 0.0f : cs[j];
    }
}

// Kernel 3: per-row denom gather (L2-resident) + loss reduce.
__global__ __launch_bounds__(256) void finalize_kernel(
    const float* __restrict__ part, const float* __restrict__ pos,
    float* __restrict__ out)
{
    int g = blockIdx.x * 256 + threadIdx.x;      // 0..8191
    int v = g >> 12, r = g & (N_ROWS - 1);
    int b = r >> 7, l = r & 127;
    const float* P = part + (size_t)v * NTILES * PSTRIDE;

    float d = 0.f;
    int t0 = b * NT - (b * (b - 1)) / 2;         // tile (b, b)
    for (int k = 0; k < NT - b; ++k) {           // row parts: tiles (b, bx>=b)
        const float* T = P + (size_t)(t0 + k) * PSTRIDE;
        d += T[l] + T[128 + l];                  // both wx halves
    }
    for (int by = 0; by <= b; ++by) {            // col parts: tiles (by<=b, b)
        int tb = by * NT - (by * (by - 1)) / 2 + (b - by);
        const float* T = P + (size_t)tb * PSTRIDE;
        d += T[256 + l] + T[384 + l];            // both wy halves
    }
    float p = pos[r];
    float s = __logf(d + __expf(p)) - p;
    #pragma unroll
    for (int off = 1; off < 64; off <<= 1) s += __shfl_xor(s, off);
    if ((threadIdx.x & 63) == 0)
        atomicAdd(out, s * (1.0f / (2 * N_ROWS)));
}

extern "C" void kernel_launch(void* const* d_in, const int* in_sizes, int n_in,
                              void* d_out, int out_size, void* d_ws, size_t ws_size,
                              hipStream_t stream) {
    const float* z_i = (const float*)d_in[0];
    const float* z_j = (const float*)d_in[1];
    char* ws = (char*)d_ws;
    unsigned short* R0 = (unsigned short*)ws;                        // 2 MB
    unsigned short* R1 = (unsigned short*)(ws + (2u << 20));         // 2 MB
    float* pos  = (float*)(ws + (4u << 20));                         // 16 KB
    float* part = (float*)(ws + (4u << 20) + (64u << 10));           // 2.1 MB

    normalize_kernel<<<N_ROWS / 4, 256, 0, stream>>>(z_i, z_j, R0, R1, pos,
                                                     (float*)d_out);
    dim3 grid(NTILES, 2);
    gemm_sym<<<grid, 256, 0, stream>>>(R0, R1, part);
    finalize_kernel<<<2 * N_ROWS / 256, 256, 0, stream>>>(part, pos, (float*)d_out);
}

// Round 11
// 88.005 us; speedup vs baseline: 1.2572x; 1.1211x over previous
//
#include <hip/hip_runtime.h>
#include <math.h>

#define N_ROWS 4096
#define DIM 256
constexpr float INV_T = 10.0f;

#define NT 32                   // 4096 / 128 tiles per view side
#define NTILES 528              // NT*(NT+1)/2 upper-triangular tiles
#define BM 128
#define PSTRIDE 512             // [2x128 row partials (per wx) | 2x128 col partials (per wy)]

typedef __attribute__((ext_vector_type(4))) float floatx4;  // fp32x4 accumulator

typedef __attribute__((address_space(3))) unsigned int lds_uint;
typedef const __attribute__((address_space(1))) unsigned int glb_uint;

// Kernel 1: one wave per row. L2-normalize; write fp8 e4m3 row-major
// (256 B/row) to R0 (zj_n) / R1 (zi_n); pos[r] = dot(zi_n,zj_n)*10 in fp32.
// Thread (0,0) zeroes the scalar output.
__global__ __launch_bounds__(256) void normalize_kernel(
    const float* __restrict__ z_i, const float* __restrict__ z_j,
    unsigned char* __restrict__ R0, unsigned char* __restrict__ R1,
    float* __restrict__ pos, float* __restrict__ out)
{
    if (blockIdx.x == 0 && threadIdx.x == 0) out[0] = 0.0f;

    int wave = threadIdx.x >> 6;
    int lane = threadIdx.x & 63;
    int row = blockIdx.x * 4 + wave;

    float4 a = ((const float4*)(z_i + (size_t)row * DIM))[lane];   // k = lane*4..+3
    float4 b = ((const float4*)(z_j + (size_t)row * DIM))[lane];

    float ssa = a.x*a.x + a.y*a.y + a.z*a.z + a.w*a.w;
    float ssb = b.x*b.x + b.y*b.y + b.z*b.z + b.w*b.w;
    float dab = a.x*b.x + a.y*b.y + a.z*b.z + a.w*b.w;
    #pragma unroll
    for (int off = 1; off < 64; off <<= 1) {
        ssa += __shfl_xor(ssa, off);
        ssb += __shfl_xor(ssb, off);
        dab += __shfl_xor(dab, off);
    }
    float ra = rsqrtf(ssa);
    float rb = rsqrtf(ssb);

    // pack 4 normalized floats -> 4 fp8 e4m3 bytes (HW cvt, OCP on gfx950)
    int va = __builtin_amdgcn_cvt_pk_fp8_f32(a.x * ra, a.y * ra, 0, false);
    va     = __builtin_amdgcn_cvt_pk_fp8_f32(a.z * ra, a.w * ra, va, true);
    int vb = __builtin_amdgcn_cvt_pk_fp8_f32(b.x * rb, b.y * rb, 0, false);
    vb     = __builtin_amdgcn_cvt_pk_fp8_f32(b.z * rb, b.w * rb, vb, true);

    *(int*)(R1 + (size_t)row * DIM + lane * 4) = va;   // zi_norm
    *(int*)(R0 + (size_t)row * DIM + lane * 4) = vb;   // zj_norm

    if (lane == 0) pos[row] = dab * ra * rb * INV_T;
}

// Kernel 2: symmetric fused fp8 GEMM, upper-triangular 128x128 tiles (x2 views).
// ONE-SHOT full-K staging: both 32 KB fp8 tiles DMA'd to LDS via
// global_load_lds(16B), then a SINGLE vmcnt(0)+barrier, then 8 uninterrupted
// K-steps (ds_read_b64 frags + mfma_f32_16x16x32_fp8_fp8) -- no convoy.
// Source-side swizzle at 16B granularity: LDS slot16 p of row r holds source
// chunk16 p^(r&15); b64 frag reads then alias <=2-way (free, m136).
// Epilogue: exp(10*S), diagonal excluded; ROW partials per (tile,wx-wave),
// COL partials per (tile,wy-wave), plain stores, unique slot per wave.
// No atomics, no counter, no fence. 64 KB LDS -> 2 blocks/CU.
__global__ __launch_bounds__(256) void gemm_sym(
    const unsigned char* __restrict__ R0,
    const unsigned char* __restrict__ R1,
    float* __restrict__ part)             // [2][NTILES][PSTRIDE]
{
    __shared__ unsigned char As[BM * DIM];   // 32 KB
    __shared__ unsigned char Bs[BM * DIM];   // 32 KB

    int view = blockIdx.y;
    const unsigned char* R = view ? R1 : R0;
    float* P = part + (size_t)(view * NTILES + blockIdx.x) * PSTRIDE;

    // triangular decode: blockIdx.x -> (by, bx), bx >= by
    int t = blockIdx.x;
    int by = 0;
    while (t >= NT - by) { t -= NT - by; ++by; }
    int bx = by + t;
    int rT = by * BM, cT = bx * BM;

    int tid = threadIdx.x;
    int lane = tid & 63;
    int wave = tid >> 6;
    int wy = wave >> 1, wx = wave & 1;
    int m = lane & 15, q = lane >> 4;

    // Stage both tiles: 2048 16B-slots each (128 rows x 16 chunk16).
    #pragma unroll
    for (int stp = 0; stp < 8; ++stp) {
        int s = stp * 256 + tid;              // lane-contiguous slot id
        int row = s >> 4, p = s & 15;
        int cg = p ^ (row & 15);              // source chunk16 for this slot
        const unsigned char* ga = R + (size_t)(rT + row) * DIM + cg * 16;
        const unsigned char* gb = R + (size_t)(cT + row) * DIM + cg * 16;
        __builtin_amdgcn_global_load_lds((glb_uint*)ga, (lds_uint*)&As[s * 16], 16, 0, 0);
        __builtin_amdgcn_global_load_lds((glb_uint*)gb, (lds_uint*)&Bs[s * 16], 16, 0, 0);
    }
    __syncthreads();   // the ONLY barrier (compiler adds the vmcnt(0) drain here)

    floatx4 acc[4][4] = {};

    #pragma unroll
    for (int kk = 0; kk < 8; ++kk) {
        long af[4], bf[4];
        int c = kk * 4 + q;                   // 8B chunk index 0..31
        int ch = c >> 1, hh = (c & 1) * 8;    // chunk16, half offset
        #pragma unroll
        for (int tt = 0; tt < 4; ++tt) {
            int ra = wy * 64 + tt * 16 + m;
            af[tt] = *(const long*)&As[ra * DIM + (ch ^ (ra & 15)) * 16 + hh];
            int rb = wx * 64 + tt * 16 + m;
            bf[tt] = *(const long*)&Bs[rb * DIM + (ch ^ (rb & 15)) * 16 + hh];
        }
        #pragma unroll
        for (int i = 0; i < 4; ++i)
            #pragma unroll
            for (int j = 0; j < 4; ++j)
                acc[i][j] = __builtin_amdgcn_mfma_f32_16x16x32_fp8_fp8(af[i], bf[j], acc[i][j], 0, 0, 0);
    }

    // Epilogue. C/D layout: col = m, row = q*4 + r (m89/m91, dtype-independent).
    float rs[4][4] = {};
    float cs[4] = {0.f, 0.f, 0.f, 0.f};
    #pragma unroll
    for (int i = 0; i < 4; ++i) {
        #pragma unroll
        for (int j = 0; j < 4; ++j) {
            int gcol = cT + wx * 64 + j * 16 + m;
            #pragma unroll
            for (int r = 0; r < 4; ++r) {
                int grow = rT + wy * 64 + i * 16 + q * 4 + r;
                float e = (grow == gcol) ? 0.0f : __expf(acc[i][j][r] * INV_T);
                rs[i][r] += e;
                cs[j] += e;
            }
        }
    }
    // Row partials: reduce over the 16 column-lanes (m); per-(wx,wy) slot.
    #pragma unroll
    for (int off = 1; off < 16; off <<= 1)
        #pragma unroll
        for (int i = 0; i < 4; ++i)
            #pragma unroll
            for (int r = 0; r < 4; ++r)
                rs[i][r] += __shfl_xor(rs[i][r], off);
    if (m == 0) {
        #pragma unroll
        for (int i = 0; i < 4; ++i) {
            float4 v = make_float4(rs[i][0], rs[i][1], rs[i][2], rs[i][3]);
            *(float4*)&P[wx * 128 + wy * 64 + i * 16 + q * 4] = v;
        }
    }
    // Col partials: reduce over the 4 row-quads (q); per-(wy,wx) slot.
    #pragma unroll
    for (int off = 16; off < 64; off <<= 1)
        #pragma unroll
        for (int j = 0; j < 4; ++j)
            cs[j] += __shfl_xor(cs[j], off);
    if (q == 0) {
        #pragma unroll
        for (int j = 0; j < 4; ++j)
            P[256 + wy * 128 + wx * 64 + j * 16 + m] = (bx == by) ? 0.0f : cs[j];
    }
}

// Kernel 3: per-row denom gather (L2-resident) + loss reduce.
__global__ __launch_bounds__(256) void finalize_kernel(
    const float* __restrict__ part, const float* __restrict__ pos,
    float* __restrict__ out)
{
    int g = blockIdx.x * 256 + threadIdx.x;      // 0..8191
    int v = g >> 12, r = g & (N_ROWS - 1);
    int b = r >> 7, l = r & 127;
    const float* P = part + (size_t)v * NTILES * PSTRIDE;

    float d = 0.f;
    int t0 = b * NT - (b * (b - 1)) / 2;         // tile (b, b)
    for (int k = 0; k < NT - b; ++k) {           // row parts: tiles (b, bx>=b)
        const float* T = P + (size_t)(t0 + k) * PSTRIDE;
        d += T[l] + T[128 + l];                  // both wx halves
    }
    for (int by = 0; by <= b; ++by) {            // col parts: tiles (by<=b, b)
        int tb = by * NT - (by * (by - 1)) / 2 + (b - by);
        const float* T = P + (size_t)tb * PSTRIDE;
        d += T[256 + l] + T[384 + l];            // both wy halves
    }
    float p = pos[r];
    float s = __logf(d + __expf(p)) - p;
    #pragma unroll
    for (int off = 1; off < 64; off <<= 1) s += __shfl_xor(s, off);
    if ((threadIdx.x & 63) == 0)
        atomicAdd(out, s * (1.0f / (2 * N_ROWS)));
}

extern "C" void kernel_launch(void* const* d_in, const int* in_sizes, int n_in,
                              void* d_out, int out_size, void* d_ws, size_t ws_size,
                              hipStream_t stream) {
    const float* z_i = (const float*)d_in[0];
    const float* z_j = (const float*)d_in[1];
    char* ws = (char*)d_ws;
    unsigned char* R0 = (unsigned char*)ws;                          // 1 MB fp8
    unsigned char* R1 = (unsigned char*)(ws + (1u << 20));           // 1 MB fp8
    float* pos  = (float*)(ws + (2u << 20));                         // 16 KB
    float* part = (float*)(ws + (2u << 20) + (64u << 10));           // 2.1 MB

    normalize_kernel<<<N_ROWS / 4, 256, 0, stream>>>(z_i, z_j, R0, R1, pos,
                                                     (float*)d_out);
    dim3 grid(NTILES, 2);
    gemm_sym<<<grid, 256, 0, stream>>>(R0, R1, part);
    finalize_kernel<<<2 * N_ROWS / 256, 256, 0, stream>>>(part, pos, (float*)d_out);
}